// Round 19
// baseline (103.899 us; speedup 1.0000x reference)
//
#include <hip/hip_runtime.h>
#include <hip/hip_bf16.h>

// Problem sizes (fixed by the reference): B=2, T=512, D=768, U=768
#define BB 2
#define TT 512
#define DD 768
#define UU 768
#define NR (BB*TT)               // 1024 global rows
#define CC 2.8853900817779268f   // 2*log2(e): exp2(CC*z) = e^{2z}

typedef __attribute__((ext_vector_type(8))) short short8v;
typedef __attribute__((ext_vector_type(4))) float float4v;
typedef __attribute__((ext_vector_type(4))) unsigned short ushort4v;

static __device__ __forceinline__ float fexp2(float x) { return __builtin_amdgcn_exp2f(x); }
static __device__ __forceinline__ float frcp(float x)  { return __builtin_amdgcn_rcpf(x); }
static __device__ __forceinline__ unsigned short bf16rn(float f) {
    unsigned u = __builtin_bit_cast(unsigned, f);
    u += 0x7FFFu + ((u >> 16) & 1u);
    return (unsigned short)(u >> 16);
}
static __device__ __forceinline__ float bf16tof(unsigned short h) {
    return __builtin_bit_cast(float, ((unsigned)h) << 16);
}

// ---------------------------------------------------------------------------
// Prep: split fp32 -> bf16 hi/lo.
//   z=0: W transpose+split -> WT[u][d]; z=1: U likewise;
//   z=2: x flat split (row-major); z=3: x transpose+split -> xT[d][j] (for PV)
// ---------------------------------------------------------------------------
__global__ __launch_bounds__(256) void prep_split(
    const float* __restrict__ x,
    const float* __restrict__ Wm,
    const float* __restrict__ Um,
    unsigned short* __restrict__ xhi, unsigned short* __restrict__ xlo,
    unsigned short* __restrict__ WThi, unsigned short* __restrict__ WTlo,
    unsigned short* __restrict__ UThi, unsigned short* __restrict__ UTlo,
    unsigned short* __restrict__ xThi, unsigned short* __restrict__ xTlo)
{
    const int mode = blockIdx.z;
    const int t = threadIdx.x;

    if (mode == 2) {
        const int blk = blockIdx.y * 12 + blockIdx.x;       // 0..191
        const float4* src = (const float4*)x + (size_t)blk * 1024;
        #pragma unroll
        for (int i = 0; i < 4; ++i) {
            const int idx = i * 256 + t;
            const float4 v = src[idx];
            ushort4v h, l;
            h.x = bf16rn(v.x); l.x = bf16rn(v.x - bf16tof(h.x));
            h.y = bf16rn(v.y); l.y = bf16rn(v.y - bf16tof(h.y));
            h.z = bf16rn(v.z); l.z = bf16rn(v.z - bf16tof(h.z));
            h.w = bf16rn(v.w); l.w = bf16rn(v.w - bf16tof(h.w));
            const size_t off = (size_t)blk * 4096 + (size_t)idx * 4;
            *(ushort4v*)(xhi + off) = h;
            *(ushort4v*)(xlo + off) = l;
        }
        return;
    }

    if (mode == 3) {
        __shared__ float tile[64][65];
        const int j0 = blockIdx.y * 64;     // source rows (j)
        const int d0 = blockIdx.x * 64;     // source cols (d)
        #pragma unroll
        for (int i = 0; i < 4; ++i) {
            const int f4 = i * 256 + t;
            const int r  = f4 >> 4;
            const int c4 = f4 & 15;
            const float4 v = *(const float4*)(x + (size_t)(j0 + r) * DD + d0 + c4 * 4);
            tile[r][c4 * 4 + 0] = v.x;
            tile[r][c4 * 4 + 1] = v.y;
            tile[r][c4 * 4 + 2] = v.z;
            tile[r][c4 * 4 + 3] = v.w;
        }
        __syncthreads();
        #pragma unroll
        for (int i = 0; i < 2; ++i) {
            const int cid = i * 256 + t;
            const int ur  = cid >> 3;
            const int kc  = cid & 7;
            short8v H, L;
            #pragma unroll
            for (int jj = 0; jj < 8; ++jj) {
                const float f = tile[kc * 8 + jj][ur];
                const unsigned short h = bf16rn(f);
                H[jj] = (short)h;
                L[jj] = (short)bf16rn(f - bf16tof(h));
            }
            const size_t off = (size_t)(d0 + ur) * NR + j0 + kc * 8;
            *(short8v*)(xThi + off) = H;
            *(short8v*)(xTlo + off) = L;
        }
        return;
    }

    if (blockIdx.y >= 12) return;                           // transpose grids are 12x12

    const float* __restrict__ S = (mode == 0) ? Wm : Um;    // [d][u]
    unsigned short* __restrict__ Thi = (mode == 0) ? WThi : UThi;
    unsigned short* __restrict__ Tlo = (mode == 0) ? WTlo : UTlo;

    __shared__ float tile[64][65];
    const int d0 = blockIdx.y * 64;
    const int u0 = blockIdx.x * 64;

    #pragma unroll
    for (int i = 0; i < 4; ++i) {
        const int f4 = i * 256 + t;
        const int r  = f4 >> 4;
        const int c4 = f4 & 15;
        const float4 v = *(const float4*)(S + (size_t)(d0 + r) * UU + u0 + c4 * 4);
        tile[r][c4 * 4 + 0] = v.x;
        tile[r][c4 * 4 + 1] = v.y;
        tile[r][c4 * 4 + 2] = v.z;
        tile[r][c4 * 4 + 3] = v.w;
    }
    __syncthreads();
    #pragma unroll
    for (int i = 0; i < 2; ++i) {
        const int cid = i * 256 + t;
        const int ur  = cid >> 3;
        const int kc  = cid & 7;
        short8v H, L;
        #pragma unroll
        for (int jj = 0; jj < 8; ++jj) {
            const float f = tile[kc * 8 + jj][ur];
            const unsigned short h = bf16rn(f);
            H[jj] = (short)h;
            L[jj] = (short)bf16rn(f - bf16tof(h));
        }
        const size_t off = (size_t)(u0 + ur) * DD + d0 + kc * 8;
        *(short8v*)(Thi + off) = H;
        *(short8v*)(Tlo + off) = L;
    }
}

// ---------------------------------------------------------------------------
// MFMA projection GEMM (bf16 3-term split).  A = WT/UT [u][k], B = x [r][k].
// 64x64 tile, BK=64, 4 waves (2x2), 16x16x32 bf16 MFMA, XOR-swizzled LDS.
//   mode 0: EW4[r>>2][u][r&3]    = exp2(CC*(x@W)[r][u])
//   mode 1: EUT[b][u>>2][j][u&3] = exp2(CC*((x@U)[r][u] + bu[u]))
// ---------------------------------------------------------------------------
__global__ __launch_bounds__(256) void gemm_mfma(
    const unsigned short* __restrict__ xhi, const unsigned short* __restrict__ xlo,
    const unsigned short* __restrict__ WThi, const unsigned short* __restrict__ WTlo,
    const unsigned short* __restrict__ UThi, const unsigned short* __restrict__ UTlo,
    const float* __restrict__ bu,
    float* __restrict__ EW4,
    float* __restrict__ EUT)
{
    const int mode = blockIdx.z;
    const unsigned short* __restrict__ Ahi = mode ? UThi : WThi;
    const unsigned short* __restrict__ Alo = mode ? UTlo : WTlo;

    __shared__ unsigned short lds[4 * 4096];   // [mat][row(64)][k(64)] swizzled

    const int tid  = threadIdx.x;
    const int lane = tid & 63;
    const int wid  = tid >> 6;
    const int wm   = wid >> 1, wn = wid & 1;
    const int u0   = blockIdx.y * 64;          // M tile (u), 12
    const int r0t  = blockIdx.x * 64;          // N tile (r), 16

    const int srow0 = tid >> 3;                // 0..31
    const int srow1 = srow0 + 32;
    const int sc0   = tid & 7;                 // k-chunk
    const int sw0   = (sc0 ^ (srow0 & 7)) << 3;

    short8v g0, g1, g2, g3, g4, g5, g6, g7;

#define LOADSTEP(K0) { \
    const size_t ka = (size_t)(K0) + sc0 * 8; \
    g0 = *(const short8v*)(Ahi + (size_t)(u0 + srow0) * DD + ka); \
    g1 = *(const short8v*)(Ahi + (size_t)(u0 + srow1) * DD + ka); \
    g2 = *(const short8v*)(Alo + (size_t)(u0 + srow0) * DD + ka); \
    g3 = *(const short8v*)(Alo + (size_t)(u0 + srow1) * DD + ka); \
    g4 = *(const short8v*)(xhi + (size_t)(r0t + srow0) * DD + ka); \
    g5 = *(const short8v*)(xhi + (size_t)(r0t + srow1) * DD + ka); \
    g6 = *(const short8v*)(xlo + (size_t)(r0t + srow0) * DD + ka); \
    g7 = *(const short8v*)(xlo + (size_t)(r0t + srow1) * DD + ka); }

#define WRITESTEP { \
    *(short8v*)&lds[0 * 4096 + srow0 * 64 + sw0] = g0; \
    *(short8v*)&lds[0 * 4096 + srow1 * 64 + sw0] = g1; \
    *(short8v*)&lds[1 * 4096 + srow0 * 64 + sw0] = g2; \
    *(short8v*)&lds[1 * 4096 + srow1 * 64 + sw0] = g3; \
    *(short8v*)&lds[2 * 4096 + srow0 * 64 + sw0] = g4; \
    *(short8v*)&lds[2 * 4096 + srow1 * 64 + sw0] = g5; \
    *(short8v*)&lds[3 * 4096 + srow0 * 64 + sw0] = g6; \
    *(short8v*)&lds[3 * 4096 + srow1 * 64 + sw0] = g7; }

    float4v acc[2][2] = {};

    LOADSTEP(0);
    for (int s = 0; s < 12; ++s) {
        __syncthreads();
        WRITESTEP;
        __syncthreads();
        if (s < 11) LOADSTEP((s + 1) * 64);

        short8v ah[2][2], al[2][2], bh[2][2], bl[2][2];
        #pragma unroll
        for (int f = 0; f < 2; ++f) {
            const int arow = wm * 32 + f * 16 + (lane & 15);
            const int brow = wn * 32 + f * 16 + (lane & 15);
            #pragma unroll
            for (int kk = 0; kk < 2; ++kk) {
                const int ck = kk * 4 + (lane >> 4);
                ah[f][kk] = *(const short8v*)&lds[0 * 4096 + arow * 64 + (((ck ^ (arow & 7))) << 3)];
                al[f][kk] = *(const short8v*)&lds[1 * 4096 + arow * 64 + (((ck ^ (arow & 7))) << 3)];
                bh[f][kk] = *(const short8v*)&lds[2 * 4096 + brow * 64 + (((ck ^ (brow & 7))) << 3)];
                bl[f][kk] = *(const short8v*)&lds[3 * 4096 + brow * 64 + (((ck ^ (brow & 7))) << 3)];
            }
        }
        #pragma unroll
        for (int kk = 0; kk < 2; ++kk)
            #pragma unroll
            for (int m = 0; m < 2; ++m)
                #pragma unroll
                for (int n = 0; n < 2; ++n) {
                    acc[m][n] = __builtin_amdgcn_mfma_f32_16x16x32_bf16(ah[m][kk], bh[n][kk], acc[m][n], 0, 0, 0);
                    acc[m][n] = __builtin_amdgcn_mfma_f32_16x16x32_bf16(ah[m][kk], bl[n][kk], acc[m][n], 0, 0, 0);
                    acc[m][n] = __builtin_amdgcn_mfma_f32_16x16x32_bf16(al[m][kk], bh[n][kk], acc[m][n], 0, 0, 0);
                }
    }

    // Epilogue. D-layout: col(r) = lane&15, row(u) = (lane>>4)*4 + reg.
    #pragma unroll
    for (int m = 0; m < 2; ++m) {
        #pragma unroll
        for (int n = 0; n < 2; ++n) {
            const int ub = u0 + wm * 32 + m * 16 + ((lane >> 4) << 2);
            const int r  = r0t + wn * 32 + n * 16 + (lane & 15);
            if (mode == 0) {
                float* dst = EW4 + ((size_t)(r >> 2) * UU + ub) * 4 + (r & 3);
                #pragma unroll
                for (int reg = 0; reg < 4; ++reg)
                    dst[reg * 4] = fexp2(acc[m][n][reg] * CC);
            } else {
                const int b = r >> 9, j = r & 511;
                const float4 bv = *(const float4*)(bu + ub);
                float4v o;
                o[0] = fexp2((acc[m][n][0] + bv.x) * CC);
                o[1] = fexp2((acc[m][n][1] + bv.y) * CC);
                o[2] = fexp2((acc[m][n][2] + bv.z) * CC);
                o[3] = fexp2((acc[m][n][3] + bv.w) * CC);
                *(float4v*)(EUT + (size_t)b * (UU * TT) + (size_t)(ub >> 2) * (TT * 4) + j * 4) = o;
            }
        }
    }
#undef LOADSTEP
#undef WRITESTEP
}

// ---------------------------------------------------------------------------
// Kernel B1: e-loop + softmax. 256 blocks x 512 threads; block owns 4 query
// rows; lane owns j = tid. R14 scalar 4-way reciprocal tree. NEW:
// __launch_bounds__(512, 2) lifts the compiler's occupancy-driven VGPR
// squeeze (was 40 VGPRs -> ~1 chunk of loads in flight), and the EUT stream
// uses an explicit DEPTH-2 register prefetch (8 float4 in flight).
// Writes normalized at = p/S as bf16 hi/lo for the PV GEMM.
// ---------------------------------------------------------------------------
__global__ __launch_bounds__(512, 2) void attn_esm(
    const float* __restrict__ V_a,
    const float* __restrict__ EW4,
    const float* __restrict__ EUT,
    unsigned short* __restrict__ athi,
    unsigned short* __restrict__ atlo)
{
    __shared__ float red[64];

    const int tid  = threadIdx.x;
    const int lane = tid & 63;
    const int w    = tid >> 6;

    // XCD-bijective swizzle: 256 blocks = 8 XCDs x 32.
    const int bid = blockIdx.x;
    const int blk = (bid & 7) * 32 + (bid >> 3);

    const int r0 = blk * 4;
    const int b  = r0 >> 9;

    const float4* __restrict__ ew4q = (const float4*)EW4 + (size_t)blk * UU;  // uniform
    const float4* __restrict__ vp4  = (const float4*)V_a;                     // uniform
    const float4* __restrict__ eq   = (const float4*)(EUT + (size_t)b * UU * TT) + tid;

    float acc0 = 0.f, acc1 = 0.f, acc2 = 0.f, acc3 = 0.f;

    // QUAD4 q covers u = 4q..4q+3 for all 4 rows; one rcp per row.
#define ROW4(E4, S0, S1, S2, S3, V4, F, ACC) { \
    const float d0 = fmaf((E4).x, S0.F, 1.f); \
    const float d1 = fmaf((E4).y, S1.F, 1.f); \
    const float d2 = fmaf((E4).z, S2.F, 1.f); \
    const float d3 = fmaf((E4).w, S3.F, 1.f); \
    float n01 = (V4).x * d1; n01 = fmaf((V4).y, d0, n01); \
    float n23 = (V4).z * d3; n23 = fmaf((V4).w, d2, n23); \
    const float dd01 = d0 * d1, dd23 = d2 * d3; \
    float n = n01 * dd23; n = fmaf(n23, dd01, n); \
    ACC = fmaf(n, frcp(dd01 * dd23), ACC); }
#define QUAD4(E4, q) { \
    const float4 S0 = ew4q[4 * (q)]; \
    const float4 S1 = ew4q[4 * (q) + 1]; \
    const float4 S2 = ew4q[4 * (q) + 2]; \
    const float4 S3 = ew4q[4 * (q) + 3]; \
    const float4 V4 = vp4[(q)]; \
    ROW4(E4, S0, S1, S2, S3, V4, x, acc0); \
    ROW4(E4, S0, S1, S2, S3, V4, y, acc1); \
    ROW4(E4, S0, S1, S2, S3, V4, z, acc2); \
    ROW4(E4, S0, S1, S2, S3, V4, w, acc3); }

    // chunk = 16 u = 4 quads; DEPTH-2 register prefetch (8 float4 in flight)
    float4 A0 = eq[0 * 512], A1 = eq[1 * 512], A2 = eq[2 * 512], A3 = eq[3 * 512];
    float4 B0 = eq[4 * 512], B1 = eq[5 * 512], B2 = eq[6 * 512], B3 = eq[7 * 512];
    #pragma unroll 1
    for (int c = 0; c < 46; ++c) {
        const int q = 4 * c;
        float4 T0 = eq[(size_t)(q +  8) * 512];
        float4 T1 = eq[(size_t)(q +  9) * 512];
        float4 T2 = eq[(size_t)(q + 10) * 512];
        float4 T3 = eq[(size_t)(q + 11) * 512];
        QUAD4(A0, q); QUAD4(A1, q + 1); QUAD4(A2, q + 2); QUAD4(A3, q + 3);
        A0 = B0; A1 = B1; A2 = B2; A3 = B3;
        B0 = T0; B1 = T1; B2 = T2; B3 = T3;
    }
    QUAD4(A0, 184); QUAD4(A1, 185); QUAD4(A2, 186); QUAD4(A3, 187);
    QUAD4(B0, 188); QUAD4(B1, 189); QUAD4(B2, 190); QUAD4(B3, 191);
#undef QUAD4
#undef ROW4

    // ---- softmax over j (8-wave reduce); e-max <-> acc-min ----
    float m0 = acc0, m1 = acc1, m2 = acc2, m3 = acc3;
    #pragma unroll
    for (int off = 32; off; off >>= 1) {
        m0 = fminf(m0, __shfl_xor(m0, off, 64));
        m1 = fminf(m1, __shfl_xor(m1, off, 64));
        m2 = fminf(m2, __shfl_xor(m2, off, 64));
        m3 = fminf(m3, __shfl_xor(m3, off, 64));
    }
    if (lane == 0) {
        red[0 * 8 + w] = m0; red[1 * 8 + w] = m1;
        red[2 * 8 + w] = m2; red[3 * 8 + w] = m3;
    }
    __syncthreads();
    float M0 = red[0], M1 = red[8], M2 = red[16], M3 = red[24];
    #pragma unroll
    for (int k = 1; k < 8; ++k) {
        M0 = fminf(M0, red[0 * 8 + k]);
        M1 = fminf(M1, red[1 * 8 + k]);
        M2 = fminf(M2, red[2 * 8 + k]);
        M3 = fminf(M3, red[3 * 8 + k]);
    }

    const float p0 = fexp2(CC * (M0 - acc0));
    const float p1 = fexp2(CC * (M1 - acc1));
    const float p2 = fexp2(CC * (M2 - acc2));
    const float p3 = fexp2(CC * (M3 - acc3));
    float s0 = p0, s1 = p1, s2 = p2, s3 = p3;
    #pragma unroll
    for (int off = 32; off; off >>= 1) {
        s0 += __shfl_xor(s0, off, 64);
        s1 += __shfl_xor(s1, off, 64);
        s2 += __shfl_xor(s2, off, 64);
        s3 += __shfl_xor(s3, off, 64);
    }
    __syncthreads();                    // red mins consumed before rewrite
    if (lane == 0) {
        red[32 + 0 * 8 + w] = s0; red[32 + 1 * 8 + w] = s1;
        red[32 + 2 * 8 + w] = s2; red[32 + 3 * 8 + w] = s3;
    }
    __syncthreads();
    float S0 = red[32], S1 = red[40], S2 = red[48], S3 = red[56];
    #pragma unroll
    for (int k = 1; k < 8; ++k) {
        S0 += red[32 + k];
        S1 += red[40 + k];
        S2 += red[48 + k];
        S3 += red[56 + k];
    }
    const float i0 = frcp(S0), i1 = frcp(S1), i2 = frcp(S2), i3 = frcp(S3);

    // ---- write normalized at as bf16 hi/lo (row-major [i][j]) ----
    const float a0 = p0 * i0, a1 = p1 * i1, a2 = p2 * i2, a3 = p3 * i3;
#define STORE_AT(R, A) { \
    const unsigned short h = bf16rn(A); \
    athi[(size_t)(r0 + (R)) * TT + tid] = h; \
    atlo[(size_t)(r0 + (R)) * TT + tid] = bf16rn((A) - bf16tof(h)); }
    STORE_AT(0, a0); STORE_AT(1, a1); STORE_AT(2, a2); STORE_AT(3, a3);
#undef STORE_AT
}

// ---------------------------------------------------------------------------
// Kernel B2: PV via MFMA.  out[i][d] = sum_j at[i][j] * x[j][d], per batch.
// A = xT [d][j global] (hi/lo), B = at [i][j] (hi/lo); C[d][i] frag ->
// float4 store to out[i][d..d+3]. 64x64 tile, K=512 (8 BK-steps), 3-term.
// ---------------------------------------------------------------------------
__global__ __launch_bounds__(256) void pv_mfma(
    const unsigned short* __restrict__ xThi, const unsigned short* __restrict__ xTlo,
    const unsigned short* __restrict__ athi, const unsigned short* __restrict__ atlo,
    float* __restrict__ out)
{
    __shared__ unsigned short lds[4 * 4096];

    const int tid  = threadIdx.x;
    const int lane = tid & 63;
    const int wid  = tid >> 6;
    const int wm   = wid >> 1, wn = wid & 1;
    const int d0t  = blockIdx.y * 64;          // M tile (d), 12
    const int i0t  = blockIdx.x * 64;          // N tile (i), 16
    const int b    = i0t >> 9;

    const int srow0 = tid >> 3;
    const int srow1 = srow0 + 32;
    const int sc0   = tid & 7;
    const int sw0   = (sc0 ^ (srow0 & 7)) << 3;

    short8v g0, g1, g2, g3, g4, g5, g6, g7;

#define LOADSTEP(K0) { \
    const size_t ka = (size_t)(K0) + sc0 * 8; \
    g0 = *(const short8v*)(xThi + (size_t)(d0t + srow0) * NR + b * TT + ka); \
    g1 = *(const short8v*)(xThi + (size_t)(d0t + srow1) * NR + b * TT + ka); \
    g2 = *(const short8v*)(xTlo + (size_t)(d0t + srow0) * NR + b * TT + ka); \
    g3 = *(const short8v*)(xTlo + (size_t)(d0t + srow1) * NR + b * TT + ka); \
    g4 = *(const short8v*)(athi + (size_t)(i0t + srow0) * TT + ka); \
    g5 = *(const short8v*)(athi + (size_t)(i0t + srow1) * TT + ka); \
    g6 = *(const short8v*)(atlo + (size_t)(i0t + srow0) * TT + ka); \
    g7 = *(const short8v*)(atlo + (size_t)(i0t + srow1) * TT + ka); }

#define WRITESTEP { \
    *(short8v*)&lds[0 * 4096 + srow0 * 64 + sw0] = g0; \
    *(short8v*)&lds[0 * 4096 + srow1 * 64 + sw0] = g1; \
    *(short8v*)&lds[1 * 4096 + srow0 * 64 + sw0] = g2; \
    *(short8v*)&lds[1 * 4096 + srow1 * 64 + sw0] = g3; \
    *(short8v*)&lds[2 * 4096 + srow0 * 64 + sw0] = g4; \
    *(short8v*)&lds[2 * 4096 + srow1 * 64 + sw0] = g5; \
    *(short8v*)&lds[3 * 4096 + srow0 * 64 + sw0] = g6; \
    *(short8v*)&lds[3 * 4096 + srow1 * 64 + sw0] = g7; }

    float4v acc[2][2] = {};

    LOADSTEP(0);
    for (int s = 0; s < 8; ++s) {              // K = 512
        __syncthreads();
        WRITESTEP;
        __syncthreads();
        if (s < 7) LOADSTEP((s + 1) * 64);

        short8v ah[2][2], al[2][2], bh[2][2], bl[2][2];
        #pragma unroll
        for (int f = 0; f < 2; ++f) {
            const int arow = wm * 32 + f * 16 + (lane & 15);
            const int brow = wn * 32 + f * 16 + (lane & 15);
            #pragma unroll
            for (int kk = 0; kk < 2; ++kk) {
                const int ck = kk * 4 + (lane >> 4);
                ah[f][kk] = *(const short8v*)&lds[0 * 4096 + arow * 64 + (((ck ^ (arow & 7))) << 3)];
                al[f][kk] = *(const short8v*)&lds[1 * 4096 + arow * 64 + (((ck ^ (arow & 7))) << 3)];
                bh[f][kk] = *(const short8v*)&lds[2 * 4096 + brow * 64 + (((ck ^ (brow & 7))) << 3)];
                bl[f][kk] = *(const short8v*)&lds[3 * 4096 + brow * 64 + (((ck ^ (brow & 7))) << 3)];
            }
        }
        #pragma unroll
        for (int kk = 0; kk < 2; ++kk)
            #pragma unroll
            for (int m = 0; m < 2; ++m)
                #pragma unroll
                for (int n = 0; n < 2; ++n) {
                    acc[m][n] = __builtin_amdgcn_mfma_f32_16x16x32_bf16(ah[m][kk], bh[n][kk], acc[m][n], 0, 0, 0);
                    acc[m][n] = __builtin_amdgcn_mfma_f32_16x16x32_bf16(ah[m][kk], bl[n][kk], acc[m][n], 0, 0, 0);
                    acc[m][n] = __builtin_amdgcn_mfma_f32_16x16x32_bf16(al[m][kk], bh[n][kk], acc[m][n], 0, 0, 0);
                }
    }

    // Epilogue: C[d][i] frag; col(i) = lane&15, row(d) = (lane>>4)*4 + reg.
    #pragma unroll
    for (int m = 0; m < 2; ++m) {
        #pragma unroll
        for (int n = 0; n < 2; ++n) {
            const int db = d0t + wm * 32 + m * 16 + ((lane >> 4) << 2);
            const int i  = i0t + wn * 32 + n * 16 + (lane & 15);
            float4v o;
            o[0] = acc[m][n][0]; o[1] = acc[m][n][1];
            o[2] = acc[m][n][2]; o[3] = acc[m][n][3];
            *(float4v*)(out + (size_t)i * DD + db) = o;
        }
    }
#undef LOADSTEP
#undef WRITESTEP
}

// ---------------------------------------------------------------------------
extern "C" void kernel_launch(void* const* d_in, const int* in_sizes, int n_in,
                              void* d_out, int out_size, void* d_ws, size_t ws_size,
                              hipStream_t stream)
{
    const float* x   = (const float*)d_in[0];  // (B,T,D)
    const float* V_a = (const float*)d_in[1];  // (U,)
    const float* U_a = (const float*)d_in[2];  // (D,U)
    const float* b_u = (const float*)d_in[3];  // (U,)
    const float* W_a = (const float*)d_in[4];  // (D,U)
    float* out = (float*)d_out;                // (B,T,D)

    float* EW4 = (float*)d_ws;                             // [NR/4][UU][4] f32, 3 MB
    float* EUT = EW4 + (size_t)UU * NR;                    // [B][U/4][T][4] f32, 3 MB
    unsigned short* xhi  = (unsigned short*)(EUT + (size_t)BB * UU * TT);
    unsigned short* xlo  = xhi + (size_t)NR * DD;
    unsigned short* WThi = xlo + (size_t)NR * DD;
    unsigned short* WTlo = WThi + (size_t)UU * DD;
    unsigned short* UThi = WTlo + (size_t)UU * DD;
    unsigned short* UTlo = UThi + (size_t)UU * DD;
    unsigned short* xThi = UTlo + (size_t)UU * DD;         // [DD][NR] bf16, 1.5 MB
    unsigned short* xTlo = xThi + (size_t)DD * NR;
    unsigned short* athi = xTlo + (size_t)DD * NR;         // [NR][TT] bf16, 1 MB
    unsigned short* atlo = athi + (size_t)NR * TT;

    hipLaunchKernelGGL(prep_split, dim3(12, 16, 4), dim3(256), 0, stream,
                       x, W_a, U_a, xhi, xlo, WThi, WTlo, UThi, UTlo, xThi, xTlo);

    hipLaunchKernelGGL(gemm_mfma, dim3(16, 12, 2), dim3(256), 0, stream,
                       xhi, xlo, WThi, WTlo, UThi, UTlo, b_u, EW4, EUT);

    hipLaunchKernelGGL(attn_esm, dim3(NR / 4), dim3(512), 0, stream,
                       V_a, EW4, EUT, athi, atlo);

    hipLaunchKernelGGL(pv_mfma, dim3(16, 12), dim3(256), 0, stream,
                       xThi, xTlo, athi, atlo, out);
}

// Round 20
// 76.601 us; speedup vs baseline: 1.3564x; 1.3564x over previous
//
#include <hip/hip_runtime.h>
#include <hip/hip_bf16.h>

// Problem sizes (fixed by the reference): B=2, T=512, D=768, U=768
#define BB 2
#define TT 512
#define DD 768
#define UU 768
#define NR (BB*TT)               // 1024 global rows
#define CC 2.8853900817779268f   // 2*log2(e): exp2(CC*z) = e^{2z}

typedef __attribute__((ext_vector_type(8))) short short8v;
typedef __attribute__((ext_vector_type(4))) float float4v;
typedef __attribute__((ext_vector_type(4))) unsigned short ushort4v;

static __device__ __forceinline__ float fexp2(float x) { return __builtin_amdgcn_exp2f(x); }
static __device__ __forceinline__ float frcp(float x)  { return __builtin_amdgcn_rcpf(x); }
static __device__ __forceinline__ float readlane_f(float v, int l) {
    return __builtin_bit_cast(float, __builtin_amdgcn_readlane(__builtin_bit_cast(unsigned, v), l));
}
static __device__ __forceinline__ unsigned short bf16rn(float f) {
    unsigned u = __builtin_bit_cast(unsigned, f);
    u += 0x7FFFu + ((u >> 16) & 1u);
    return (unsigned short)(u >> 16);
}
static __device__ __forceinline__ float bf16tof(unsigned short h) {
    return __builtin_bit_cast(float, ((unsigned)h) << 16);
}

// ---------------------------------------------------------------------------
// Prep: split fp32 -> bf16 hi/lo.  z=0: W transpose+split -> WT[u][d];
// z=1: U likewise; z=2: x flat split (row-major kept).
// ---------------------------------------------------------------------------
__global__ __launch_bounds__(256) void prep_split(
    const float* __restrict__ x,
    const float* __restrict__ Wm,
    const float* __restrict__ Um,
    unsigned short* __restrict__ xhi, unsigned short* __restrict__ xlo,
    unsigned short* __restrict__ WThi, unsigned short* __restrict__ WTlo,
    unsigned short* __restrict__ UThi, unsigned short* __restrict__ UTlo)
{
    const int mode = blockIdx.z;
    const int t = threadIdx.x;

    if (mode == 2) {
        const int blk = blockIdx.y * 12 + blockIdx.x;       // 0..191
        const float4* src = (const float4*)x + (size_t)blk * 1024;
        #pragma unroll
        for (int i = 0; i < 4; ++i) {
            const int idx = i * 256 + t;
            const float4 v = src[idx];
            ushort4v h, l;
            h.x = bf16rn(v.x); l.x = bf16rn(v.x - bf16tof(h.x));
            h.y = bf16rn(v.y); l.y = bf16rn(v.y - bf16tof(h.y));
            h.z = bf16rn(v.z); l.z = bf16rn(v.z - bf16tof(h.z));
            h.w = bf16rn(v.w); l.w = bf16rn(v.w - bf16tof(h.w));
            const size_t off = (size_t)blk * 4096 + (size_t)idx * 4;
            *(ushort4v*)(xhi + off) = h;
            *(ushort4v*)(xlo + off) = l;
        }
        return;
    }
    if (blockIdx.y >= 12) return;                           // transpose grids are 12x12

    const float* __restrict__ S = (mode == 0) ? Wm : Um;    // [d][u]
    unsigned short* __restrict__ Thi = (mode == 0) ? WThi : UThi;
    unsigned short* __restrict__ Tlo = (mode == 0) ? WTlo : UTlo;

    __shared__ float tile[64][65];
    const int d0 = blockIdx.y * 64;
    const int u0 = blockIdx.x * 64;

    #pragma unroll
    for (int i = 0; i < 4; ++i) {
        const int f4 = i * 256 + t;
        const int r  = f4 >> 4;
        const int c4 = f4 & 15;
        const float4 v = *(const float4*)(S + (size_t)(d0 + r) * UU + u0 + c4 * 4);
        tile[r][c4 * 4 + 0] = v.x;
        tile[r][c4 * 4 + 1] = v.y;
        tile[r][c4 * 4 + 2] = v.z;
        tile[r][c4 * 4 + 3] = v.w;
    }
    __syncthreads();
    #pragma unroll
    for (int i = 0; i < 2; ++i) {
        const int cid = i * 256 + t;
        const int ur  = cid >> 3;
        const int kc  = cid & 7;
        short8v H, L;
        #pragma unroll
        for (int j = 0; j < 8; ++j) {
            const float f = tile[kc * 8 + j][ur];
            const unsigned short h = bf16rn(f);
            H[j] = (short)h;
            L[j] = (short)bf16rn(f - bf16tof(h));
        }
        const size_t off = (size_t)(u0 + ur) * DD + d0 + kc * 8;
        *(short8v*)(Thi + off) = H;
        *(short8v*)(Tlo + off) = L;
    }
}

// ---------------------------------------------------------------------------
// MFMA projection GEMM (bf16 3-term split).  A = WT/UT [u][k], B = x [r][k].
// 64x64 tile, BK=64, 4 waves (2x2), 16x16x32 bf16 MFMA, XOR-swizzled LDS.
//   mode 0: EW4[r>>2][u][r&3]    = exp2(CC*(x@W)[r][u])
//   mode 1: EUT[b][u>>2][j][u&3] = exp2(CC*((x@U)[r][u] + bu[u]))
// ---------------------------------------------------------------------------
__global__ __launch_bounds__(256) void gemm_mfma(
    const unsigned short* __restrict__ xhi, const unsigned short* __restrict__ xlo,
    const unsigned short* __restrict__ WThi, const unsigned short* __restrict__ WTlo,
    const unsigned short* __restrict__ UThi, const unsigned short* __restrict__ UTlo,
    const float* __restrict__ bu,
    float* __restrict__ EW4,
    float* __restrict__ EUT)
{
    const int mode = blockIdx.z;
    const unsigned short* __restrict__ Ahi = mode ? UThi : WThi;
    const unsigned short* __restrict__ Alo = mode ? UTlo : WTlo;

    __shared__ unsigned short lds[4 * 4096];   // [mat][row(64)][k(64)] swizzled

    const int tid  = threadIdx.x;
    const int lane = tid & 63;
    const int wid  = tid >> 6;
    const int wm   = wid >> 1, wn = wid & 1;
    const int u0   = blockIdx.y * 64;          // M tile (u), 12
    const int r0t  = blockIdx.x * 64;          // N tile (r), 16

    const int srow0 = tid >> 3;                // 0..31
    const int srow1 = srow0 + 32;
    const int sc0   = tid & 7;                 // k-chunk
    const int sw0   = (sc0 ^ (srow0 & 7)) << 3;

    short8v g0, g1, g2, g3, g4, g5, g6, g7;

#define LOADSTEP(K0) { \
    const size_t ka = (size_t)(K0) + sc0 * 8; \
    g0 = *(const short8v*)(Ahi + (size_t)(u0 + srow0) * DD + ka); \
    g1 = *(const short8v*)(Ahi + (size_t)(u0 + srow1) * DD + ka); \
    g2 = *(const short8v*)(Alo + (size_t)(u0 + srow0) * DD + ka); \
    g3 = *(const short8v*)(Alo + (size_t)(u0 + srow1) * DD + ka); \
    g4 = *(const short8v*)(xhi + (size_t)(r0t + srow0) * DD + ka); \
    g5 = *(const short8v*)(xhi + (size_t)(r0t + srow1) * DD + ka); \
    g6 = *(const short8v*)(xlo + (size_t)(r0t + srow0) * DD + ka); \
    g7 = *(const short8v*)(xlo + (size_t)(r0t + srow1) * DD + ka); }

#define WRITESTEP { \
    *(short8v*)&lds[0 * 4096 + srow0 * 64 + sw0] = g0; \
    *(short8v*)&lds[0 * 4096 + srow1 * 64 + sw0] = g1; \
    *(short8v*)&lds[1 * 4096 + srow0 * 64 + sw0] = g2; \
    *(short8v*)&lds[1 * 4096 + srow1 * 64 + sw0] = g3; \
    *(short8v*)&lds[2 * 4096 + srow0 * 64 + sw0] = g4; \
    *(short8v*)&lds[2 * 4096 + srow1 * 64 + sw0] = g5; \
    *(short8v*)&lds[3 * 4096 + srow0 * 64 + sw0] = g6; \
    *(short8v*)&lds[3 * 4096 + srow1 * 64 + sw0] = g7; }

    float4v acc[2][2] = {};

    LOADSTEP(0);
    for (int s = 0; s < 12; ++s) {
        __syncthreads();
        WRITESTEP;
        __syncthreads();
        if (s < 11) LOADSTEP((s + 1) * 64);

        short8v ah[2][2], al[2][2], bh[2][2], bl[2][2];
        #pragma unroll
        for (int f = 0; f < 2; ++f) {
            const int arow = wm * 32 + f * 16 + (lane & 15);
            const int brow = wn * 32 + f * 16 + (lane & 15);
            #pragma unroll
            for (int kk = 0; kk < 2; ++kk) {
                const int ck = kk * 4 + (lane >> 4);
                ah[f][kk] = *(const short8v*)&lds[0 * 4096 + arow * 64 + (((ck ^ (arow & 7))) << 3)];
                al[f][kk] = *(const short8v*)&lds[1 * 4096 + arow * 64 + (((ck ^ (arow & 7))) << 3)];
                bh[f][kk] = *(const short8v*)&lds[2 * 4096 + brow * 64 + (((ck ^ (brow & 7))) << 3)];
                bl[f][kk] = *(const short8v*)&lds[3 * 4096 + brow * 64 + (((ck ^ (brow & 7))) << 3)];
            }
        }
        #pragma unroll
        for (int kk = 0; kk < 2; ++kk)
            #pragma unroll
            for (int m = 0; m < 2; ++m)
                #pragma unroll
                for (int n = 0; n < 2; ++n) {
                    acc[m][n] = __builtin_amdgcn_mfma_f32_16x16x32_bf16(ah[m][kk], bh[n][kk], acc[m][n], 0, 0, 0);
                    acc[m][n] = __builtin_amdgcn_mfma_f32_16x16x32_bf16(ah[m][kk], bl[n][kk], acc[m][n], 0, 0, 0);
                    acc[m][n] = __builtin_amdgcn_mfma_f32_16x16x32_bf16(al[m][kk], bh[n][kk], acc[m][n], 0, 0, 0);
                }
    }

    // Epilogue. D-layout: col(r) = lane&15, row(u) = (lane>>4)*4 + reg.
    #pragma unroll
    for (int m = 0; m < 2; ++m) {
        #pragma unroll
        for (int n = 0; n < 2; ++n) {
            const int ub = u0 + wm * 32 + m * 16 + ((lane >> 4) << 2);
            const int r  = r0t + wn * 32 + n * 16 + (lane & 15);
            if (mode == 0) {
                float* dst = EW4 + ((size_t)(r >> 2) * UU + ub) * 4 + (r & 3);
                #pragma unroll
                for (int reg = 0; reg < 4; ++reg)
                    dst[reg * 4] = fexp2(acc[m][n][reg] * CC);
            } else {
                const int b = r >> 9, j = r & 511;
                const float4 bv = *(const float4*)(bu + ub);
                float4v o;
                o[0] = fexp2((acc[m][n][0] + bv.x) * CC);
                o[1] = fexp2((acc[m][n][1] + bv.y) * CC);
                o[2] = fexp2((acc[m][n][2] + bv.z) * CC);
                o[3] = fexp2((acc[m][n][3] + bv.w) * CC);
                *(float4v*)(EUT + (size_t)b * (UU * TT) + (size_t)(ub >> 2) * (TT * 4) + j * 4) = o;
            }
        }
    }
#undef LOADSTEP
#undef WRITESTEP
}

// ---------------------------------------------------------------------------
// Kernel B: fused e / softmax / PV  (R14 configuration -- best measured).
// 256 blocks x 512 threads (1 block/CU); block owns 4 query rows; lane owns
// j = tid. E-loop: no LDS, <=1 SGPR operand per VALU op, 4-WAY reciprocal
// tree (one v_rcp per 4 products):
//   d_i = fma(E_i, s_i, 1.0); n01 = v0*d1 + v1*d0; n23 = v2*d3 + v3*d2;
//   acc += (n01*dd23 + n23*dd01) * rcp(dd01*dd23)
// PV: wave w owns j in [64w,64w+64); at via readlane; 2-pass LDS reduction.
// ---------------------------------------------------------------------------
__global__ __launch_bounds__(512) void attn_fused(
    const float* __restrict__ x,
    const float* __restrict__ V_a,
    const float* __restrict__ EW4,
    const float* __restrict__ EUT,
    float* __restrict__ out)
{
    extern __shared__ float smem[];
    float* part = smem;                 // [8][2][768] = 12288 (PV phase)
    float* red  = smem;                 // 64 (softmax phase; aliases part)

    const int tid  = threadIdx.x;
    const int lane = tid & 63;
    const int w    = tid >> 6;

    // XCD-bijective swizzle: 256 blocks = 8 XCDs x 32.
    const int bid = blockIdx.x;
    const int blk = (bid & 7) * 32 + (bid >> 3);

    const int r0 = blk * 4;
    const int b  = r0 >> 9;

    const float4* __restrict__ ew4q = (const float4*)EW4 + (size_t)blk * UU;  // uniform
    const float4* __restrict__ vp4  = (const float4*)V_a;                     // uniform
    const float4* __restrict__ eq   = (const float4*)(EUT + (size_t)b * UU * TT) + tid;

    float acc0 = 0.f, acc1 = 0.f, acc2 = 0.f, acc3 = 0.f;

    // QUAD4 q covers u = 4q..4q+3 for all 4 rows; one rcp per row.
#define ROW4(E4, S0, S1, S2, S3, V4, F, ACC) { \
    const float d0 = fmaf((E4).x, S0.F, 1.f); \
    const float d1 = fmaf((E4).y, S1.F, 1.f); \
    const float d2 = fmaf((E4).z, S2.F, 1.f); \
    const float d3 = fmaf((E4).w, S3.F, 1.f); \
    float n01 = (V4).x * d1; n01 = fmaf((V4).y, d0, n01); \
    float n23 = (V4).z * d3; n23 = fmaf((V4).w, d2, n23); \
    const float dd01 = d0 * d1, dd23 = d2 * d3; \
    float n = n01 * dd23; n = fmaf(n23, dd01, n); \
    ACC = fmaf(n, frcp(dd01 * dd23), ACC); }
#define QUAD4(E4, q) { \
    const float4 S0 = ew4q[4 * (q)]; \
    const float4 S1 = ew4q[4 * (q) + 1]; \
    const float4 S2 = ew4q[4 * (q) + 2]; \
    const float4 S3 = ew4q[4 * (q) + 3]; \
    const float4 V4 = vp4[(q)]; \
    ROW4(E4, S0, S1, S2, S3, V4, x, acc0); \
    ROW4(E4, S0, S1, S2, S3, V4, y, acc1); \
    ROW4(E4, S0, S1, S2, S3, V4, z, acc2); \
    ROW4(E4, S0, S1, S2, S3, V4, w, acc3); }

    // chunk = 16 u = 4 quads; depth-1 register prefetch
    float4 c0 = eq[0 * 512], c1 = eq[1 * 512], c2 = eq[2 * 512], c3 = eq[3 * 512];
    #pragma unroll 1
    for (int c = 0; c < 47; ++c) {
        const int q = 4 * c;
        float4 n0_ = eq[(size_t)(q + 4) * 512];
        float4 n1_ = eq[(size_t)(q + 5) * 512];
        float4 n2_ = eq[(size_t)(q + 6) * 512];
        float4 n3_ = eq[(size_t)(q + 7) * 512];
        QUAD4(c0, q); QUAD4(c1, q + 1); QUAD4(c2, q + 2); QUAD4(c3, q + 3);
        c0 = n0_; c1 = n1_; c2 = n2_; c3 = n3_;
    }
    QUAD4(c0, 188); QUAD4(c1, 189); QUAD4(c2, 190); QUAD4(c3, 191);
#undef QUAD4
#undef ROW4

    // ---- softmax over j (8-wave reduce); e-max <-> acc-min ----
    float m0 = acc0, m1 = acc1, m2 = acc2, m3 = acc3;
    #pragma unroll
    for (int off = 32; off; off >>= 1) {
        m0 = fminf(m0, __shfl_xor(m0, off, 64));
        m1 = fminf(m1, __shfl_xor(m1, off, 64));
        m2 = fminf(m2, __shfl_xor(m2, off, 64));
        m3 = fminf(m3, __shfl_xor(m3, off, 64));
    }
    if (lane == 0) {
        red[0 * 8 + w] = m0; red[1 * 8 + w] = m1;
        red[2 * 8 + w] = m2; red[3 * 8 + w] = m3;
    }
    __syncthreads();
    float M0 = red[0], M1 = red[8], M2 = red[16], M3 = red[24];
    #pragma unroll
    for (int k = 1; k < 8; ++k) {
        M0 = fminf(M0, red[0 * 8 + k]);
        M1 = fminf(M1, red[1 * 8 + k]);
        M2 = fminf(M2, red[2 * 8 + k]);
        M3 = fminf(M3, red[3 * 8 + k]);
    }

    const float p0 = fexp2(CC * (M0 - acc0));
    const float p1 = fexp2(CC * (M1 - acc1));
    const float p2 = fexp2(CC * (M2 - acc2));
    const float p3 = fexp2(CC * (M3 - acc3));
    float s0 = p0, s1 = p1, s2 = p2, s3 = p3;
    #pragma unroll
    for (int off = 32; off; off >>= 1) {
        s0 += __shfl_xor(s0, off, 64);
        s1 += __shfl_xor(s1, off, 64);
        s2 += __shfl_xor(s2, off, 64);
        s3 += __shfl_xor(s3, off, 64);
    }
    __syncthreads();                    // red mins consumed before rewrite
    if (lane == 0) {
        red[32 + 0 * 8 + w] = s0; red[32 + 1 * 8 + w] = s1;
        red[32 + 2 * 8 + w] = s2; red[32 + 3 * 8 + w] = s3;
    }
    __syncthreads();
    float S0 = red[32], S1 = red[40], S2 = red[48], S3 = red[56];
    #pragma unroll
    for (int k = 1; k < 8; ++k) {
        S0 += red[32 + k];
        S1 += red[40 + k];
        S2 += red[48 + k];
        S3 += red[56 + k];
    }
    const float i0 = frcp(S0), i1 = frcp(S1), i2 = frcp(S2), i3 = frcp(S3);

    // ---- PV (j-partition): wave w handles j in [64w, 64w+64) ----
    const float* __restrict__ xb = x + (size_t)b * TT * DD + (size_t)w * 64 * DD + 4 * lane;
    float4 z4 = {0.f, 0.f, 0.f, 0.f};
    float4 pc00 = z4, pc01 = z4, pc02 = z4;
    float4 pc10 = z4, pc11 = z4, pc12 = z4;
    float4 pc20 = z4, pc21 = z4, pc22 = z4;
    float4 pc30 = z4, pc31 = z4, pc32 = z4;

#define F4(dst, a, xv) { dst.x = fmaf(a, xv.x, dst.x); dst.y = fmaf(a, xv.y, dst.y); \
                         dst.z = fmaf(a, xv.z, dst.z); dst.w = fmaf(a, xv.w, dst.w); }
    #pragma unroll 2
    for (int jj = 0; jj < 64; ++jj) {
        const float a0 = readlane_f(p0, jj);
        const float a1 = readlane_f(p1, jj);
        const float a2 = readlane_f(p2, jj);
        const float a3 = readlane_f(p3, jj);
        const float* xr = xb + (size_t)jj * DD;
        const float4 x0 = *(const float4*)(xr);
        const float4 x1 = *(const float4*)(xr + 256);
        const float4 x2 = *(const float4*)(xr + 512);
        F4(pc00, a0, x0); F4(pc01, a0, x1); F4(pc02, a0, x2);
        F4(pc10, a1, x0); F4(pc11, a1, x1); F4(pc12, a1, x2);
        F4(pc20, a2, x0); F4(pc21, a2, x1); F4(pc22, a2, x2);
        F4(pc30, a3, x0); F4(pc31, a3, x1); F4(pc32, a3, x2);
    }
#undef F4

    __syncthreads();                    // softmax reds done before part reuse
    {
        float* pw = part + w * 1536 + 4 * lane;
        *(float4*)(pw + 0)    = pc00;
        *(float4*)(pw + 256)  = pc01;
        *(float4*)(pw + 512)  = pc02;
        *(float4*)(pw + 768)  = pc10;
        *(float4*)(pw + 1024) = pc11;
        *(float4*)(pw + 1280) = pc12;
    }
    __syncthreads();
    #pragma unroll
    for (int e = 0; e < 3; ++e) {
        const int idx = e * 512 + tid;          // 0..1535
        const int r   = (idx >= 768) ? 1 : 0;
        const int d   = idx - r * 768;
        float ssum = 0.f;
        #pragma unroll
        for (int w2 = 0; w2 < 8; ++w2) ssum += part[w2 * 1536 + r * 768 + d];
        out[(size_t)(r0 + r) * DD + d] = ssum * (r ? i1 : i0);
    }
    __syncthreads();
    {
        float* pw = part + w * 1536 + 4 * lane;
        *(float4*)(pw + 0)    = pc20;
        *(float4*)(pw + 256)  = pc21;
        *(float4*)(pw + 512)  = pc22;
        *(float4*)(pw + 768)  = pc30;
        *(float4*)(pw + 1024) = pc31;
        *(float4*)(pw + 1280) = pc32;
    }
    __syncthreads();
    #pragma unroll
    for (int e = 0; e < 3; ++e) {
        const int idx = e * 512 + tid;
        const int r   = (idx >= 768) ? 1 : 0;
        const int d   = idx - r * 768;
        float ssum = 0.f;
        #pragma unroll
        for (int w2 = 0; w2 < 8; ++w2) ssum += part[w2 * 1536 + r * 768 + d];
        out[(size_t)(r0 + 2 + r) * DD + d] = ssum * (r ? i3 : i2);
    }
}

// ---------------------------------------------------------------------------
extern "C" void kernel_launch(void* const* d_in, const int* in_sizes, int n_in,
                              void* d_out, int out_size, void* d_ws, size_t ws_size,
                              hipStream_t stream)
{
    const float* x   = (const float*)d_in[0];  // (B,T,D)
    const float* V_a = (const float*)d_in[1];  // (U,)
    const float* U_a = (const float*)d_in[2];  // (D,U)
    const float* b_u = (const float*)d_in[3];  // (U,)
    const float* W_a = (const float*)d_in[4];  // (D,U)
    float* out = (float*)d_out;                // (B,T,D)

    float* EW4 = (float*)d_ws;                             // [NR/4][UU][4] f32, 3 MB
    float* EUT = EW4 + (size_t)UU * NR;                    // [B][U/4][T][4] f32, 3 MB
    unsigned short* xhi  = (unsigned short*)(EUT + (size_t)BB * UU * TT);
    unsigned short* xlo  = xhi + (size_t)NR * DD;
    unsigned short* WThi = xlo + (size_t)NR * DD;
    unsigned short* WTlo = WThi + (size_t)UU * DD;
    unsigned short* UThi = WTlo + (size_t)UU * DD;
    unsigned short* UTlo = UThi + (size_t)UU * DD;

    hipLaunchKernelGGL(prep_split, dim3(12, 16, 3), dim3(256), 0, stream,
                       x, W_a, U_a, xhi, xlo, WThi, WTlo, UThi, UTlo);

    hipLaunchKernelGGL(gemm_mfma, dim3(16, 12, 2), dim3(256), 0, stream,
                       xhi, xlo, WThi, WTlo, UThi, UTlo, b_u, EW4, EUT);

    const int ldsB = 12288 * sizeof(float);                // 49152 B
    hipLaunchKernelGGL(attn_fused, dim3(NR / 4), dim3(512), ldsB, stream,
                       x, V_a, EW4, EUT, out);
}